// Round 1
// 1069.322 us; speedup vs baseline: 1.1554x; 1.1554x over previous
//
#include <hip/hip_runtime.h>
#include <hip/hip_bf16.h>
#include <math.h>

#define F 64
#define TPB 256
#define MTILE 256          // edges per tile (4 waves x 64)
#define BN_EPS 1e-5f
#define LGRID 512          // persistent blocks for layer kernels (2/CU)

typedef __attribute__((ext_vector_type(8))) short short8;   // 8 bf16 (4 VGPRs)
typedef __attribute__((ext_vector_type(4))) float f32x4;

__device__ __forceinline__ float sp(float x) {
    // stable softplus = max(x,0) + log1p(exp(-|x|))
    return fmaxf(x, 0.f) + __logf(1.f + __expf(-fabsf(x)));
}
__device__ __forceinline__ ushort f2bf(float f) {
    __hip_bfloat16 h = __float2bfloat16(f);
    return *reinterpret_cast<ushort*>(&h);
}
__device__ __forceinline__ float bf2f(ushort u) {
    unsigned v = ((unsigned)u) << 16;
    return __builtin_bit_cast(float, v);
}

// One dense layer via MFMA, persistent-block version.
// - grid-stride over 256-edge tiles; W^T staged to LDS once per block
// - BN stats accumulated in registers across tiles, reduced once at end
// - software pipeline: convert staged raw regs -> bf16 b-frags, then issue
//   next tile's loads (WAR on the staging regs orders them after the
//   convert); loads complete under the MFMA + store + stats work.
// - Linear bias DROPPED: bias cancels under BatchNorm (mean shifts by b,
//   variance unchanged), so unbiased Y + unbiased stats give identical
//   downstream affine (a = gamma*rsqrt(var+eps), c = beta - mu*a).
template <int HAS_ACT>
__global__ __launch_bounds__(TPB, 2)
void layer_mfma(const void* __restrict__ Xv, uint2* __restrict__ Yg,
                const float* __restrict__ W,
                const float* __restrict__ prev_stats,
                const float* __restrict__ gamma_prev,
                const float* __restrict__ beta_prev,
                float* __restrict__ stats_out, int E)
{
    __shared__ short8 Wt[512];        // W^T blocked: unit(kq,n)=kq*64+n, 8 KB
    __shared__ float aca[F], acb[F];  // BN affine a, c (prev layer)
    __shared__ float sh_s[F], sh_q[F];

    const int t  = threadIdx.x;
    const int w  = t >> 6;        // wave 0..3  (m-range)
    const int l  = t & 63;        // lane
    const int ln = l & 15;
    const int q  = l >> 4;        // quad

    // ---- stage W^T (bf16, blocked by k-groups of 8) — once per block ----
    #pragma unroll
    for (int uu = 0; uu < 2; ++uu) {
        int u = t + uu * 256;
        int kq = u >> 6, n = u & 63;
        short8 pk;
        #pragma unroll
        for (int j = 0; j < 8; ++j)
            pk[j] = (short)f2bf(W[(kq * 8 + j) * F + n]);
        Wt[u] = pk;
    }
    if (t < F) {
        sh_s[t] = 0.f; sh_q[t] = 0.f;
        if (HAS_ACT) {
            float inv_e = 1.f / (float)E;
            float mu = prev_stats[t] * inv_e;
            float var = prev_stats[F + t] * inv_e - mu * mu;
            float a = gamma_prev[t] * rsqrtf(var + BN_EPS);
            aca[t] = a;
            acb[t] = beta_prev[t] - mu * a;
        }
    }
    __syncthreads();

    // A-frags (W^T): lane holds W[k=32ks+8q+j][n=ni*16+ln]
    short8 afr[4][2];
    #pragma unroll
    for (int ni = 0; ni < 4; ++ni)
        #pragma unroll
        for (int ks = 0; ks < 2; ++ks)
            afr[ni][ks] = Wt[(4 * ks + q) * 64 + ni * 16 + ln];

    // per-thread BN stats accumulators, persist across tiles
    float ps[16], pq[16];
    #pragma unroll
    for (int p = 0; p < 16; ++p) { ps[p] = 0.f; pq[p] = 0.f; }

    const int ntiles = E >> 8;   // E / MTILE

    // raw staged inputs (double-duty regs: hold tile i during convert,
    // then refilled with tile i+LGRID during compute)
    uint2  xb_a[4][2][2];   // HAS_ACT path (bf16 blocked input)
    float4 xb_f[4][2][2];   // layer-1 path (fp32 row-major input)

    // ---- prologue: load first tile ----
    {
        const long e00 = (long)blockIdx.x * MTILE + w * 64;
        #pragma unroll
        for (int mi = 0; mi < 4; ++mi) {
            const long e = e00 + mi * 16 + ln;
            #pragma unroll
            for (int ks = 0; ks < 2; ++ks) {
                if (HAS_ACT) {
                    const uint2* X = (const uint2*)Xv;
                    xb_a[mi][ks][0] = X[(size_t)(8 * ks + 2 * q) * E + e];
                    xb_a[mi][ks][1] = X[(size_t)(8 * ks + 2 * q + 1) * E + e];
                } else {
                    const float4* X4 = (const float4*)Xv;
                    xb_f[mi][ks][0] = X4[(size_t)e * 16 + 8 * ks + 2 * q];
                    xb_f[mi][ks][1] = X4[(size_t)e * 16 + 8 * ks + 2 * q + 1];
                }
            }
        }
    }

    #pragma unroll 1
    for (int tile = blockIdx.x; tile < ntiles; tile += LGRID) {
        const long e0 = (long)tile * MTILE + w * 64;

        // ---- convert staged raw -> b-frags (frees xb for prefetch) ----
        short8 bfr[4][2];
        #pragma unroll
        for (int mi = 0; mi < 4; ++mi)
            #pragma unroll
            for (int ks = 0; ks < 2; ++ks) {
                short8 b;
                if (HAS_ACT) {
                    uint vs[4] = {xb_a[mi][ks][0].x, xb_a[mi][ks][0].y,
                                  xb_a[mi][ks][1].x, xb_a[mi][ks][1].y};
                    #pragma unroll
                    for (int d = 0; d < 4; ++d) {
                        // k-index of element 2d: 32ks + 8q + 2d
                        float x0 = bf2f((ushort)(vs[d] & 0xffffu));
                        float x1 = bf2f((ushort)(vs[d] >> 16));
                        int k0 = 32 * ks + 8 * q + 2 * d;
                        b[2*d]   = (short)f2bf(sp(aca[k0]     * x0 + acb[k0]));
                        b[2*d+1] = (short)f2bf(sp(aca[k0 + 1] * x1 + acb[k0 + 1]));
                    }
                } else {
                    float4 f0 = xb_f[mi][ks][0], f1 = xb_f[mi][ks][1];
                    b[0] = (short)f2bf(f0.x); b[1] = (short)f2bf(f0.y);
                    b[2] = (short)f2bf(f0.z); b[3] = (short)f2bf(f0.w);
                    b[4] = (short)f2bf(f1.x); b[5] = (short)f2bf(f1.y);
                    b[6] = (short)f2bf(f1.z); b[7] = (short)f2bf(f1.w);
                }
                bfr[mi][ks] = b;
            }

        // ---- prefetch next tile (overlaps MFMA/store below) ----
        const int tnext = tile + LGRID;
        if (tnext < ntiles) {
            const long en = (long)tnext * MTILE + w * 64;
            #pragma unroll
            for (int mi = 0; mi < 4; ++mi) {
                const long e = en + mi * 16 + ln;
                #pragma unroll
                for (int ks = 0; ks < 2; ++ks) {
                    if (HAS_ACT) {
                        const uint2* X = (const uint2*)Xv;
                        xb_a[mi][ks][0] = X[(size_t)(8 * ks + 2 * q) * E + e];
                        xb_a[mi][ks][1] = X[(size_t)(8 * ks + 2 * q + 1) * E + e];
                    } else {
                        const float4* X4 = (const float4*)Xv;
                        xb_f[mi][ks][0] = X4[(size_t)e * 16 + 8 * ks + 2 * q];
                        xb_f[mi][ks][1] = X4[(size_t)e * 16 + 8 * ks + 2 * q + 1];
                    }
                }
            }
        }

        // ---- MFMA (no bias: acc starts at 0) ----
        f32x4 acc[4][4];
        #pragma unroll
        for (int ni = 0; ni < 4; ++ni)
            #pragma unroll
            for (int mi = 0; mi < 4; ++mi)
                acc[ni][mi] = (f32x4){0.f, 0.f, 0.f, 0.f};

        #pragma unroll
        for (int mi = 0; mi < 4; ++mi)
            #pragma unroll
            for (int ks = 0; ks < 2; ++ks)
                #pragma unroll
                for (int ni = 0; ni < 4; ++ni)
                    acc[ni][mi] = __builtin_amdgcn_mfma_f32_16x16x32_bf16(
                                      afr[ni][ks], bfr[mi][ks], acc[ni][mi], 0, 0, 0);

        // ---- store (packed 4-feature units, coalesced) + stats accumulate ----
        #pragma unroll
        for (int ni = 0; ni < 4; ++ni)
            #pragma unroll
            for (int mi = 0; mi < 4; ++mi) {
                const long e = e0 + mi * 16 + ln;
                f32x4 v = acc[ni][mi];
                uint2 u;
                u.x = (uint)f2bf(v[0]) | ((uint)f2bf(v[1]) << 16);
                u.y = (uint)f2bf(v[2]) | ((uint)f2bf(v[3]) << 16);
                Yg[(size_t)(ni * 4 + q) * E + e] = u;
                #pragma unroll
                for (int r = 0; r < 4; ++r) {
                    float x = v[r];
                    ps[ni * 4 + r] += x;
                    pq[ni * 4 + r] = fmaf(x, x, pq[ni * 4 + r]);
                }
            }
    }

    // ---- stats reduction: once per block ----
    #pragma unroll
    for (int p = 0; p < 16; ++p) {
        #pragma unroll
        for (int m = 1; m < 16; m <<= 1) {
            ps[p] += __shfl_xor(ps[p], m);
            pq[p] += __shfl_xor(pq[p], m);
        }
    }
    if (ln == 0) {
        #pragma unroll
        for (int p = 0; p < 16; ++p) {
            int n = (p >> 2) * 16 + q * 4 + (p & 3);
            atomicAdd(&sh_s[n], ps[p]);
            atomicAdd(&sh_q[n], pq[p]);
        }
    }
    __syncthreads();
    if (t < F) {
        unsafeAtomicAdd(&stats_out[t], sh_s[t]);
        unsafeAtomicAdd(&stats_out[F + t], sh_q[t]);
    }
}

// Streaming: s = softplus(a*Y3 + c) . w_out + b_out, coalesced read of the
// blocked layout, coalesced write of s[E]. No gathers, no atomics.
__global__ __launch_bounds__(TPB)
void s_kernel(const uint2* __restrict__ Yg, const float* __restrict__ stats,
              const float* __restrict__ gamma, const float* __restrict__ beta,
              const float* __restrict__ w_out, const float* __restrict__ b_out,
              float* __restrict__ s_out, int E)
{
    __shared__ float ac[2 * F];
    __shared__ float wsh[F];
    const int t = threadIdx.x;
    if (t < F) {
        float inv_e = 1.f / (float)E;
        float mu = stats[t] * inv_e;
        float var = stats[F + t] * inv_e - mu * mu;
        float a = gamma[t] * rsqrtf(var + BN_EPS);
        ac[t] = a;
        ac[F + t] = beta[t] - mu * a;
        wsh[t] = w_out[t];
    }
    __syncthreads();

    const long e = (long)blockIdx.x * TPB + t;
    if (e >= E) return;

    float s = b_out[0];
    #pragma unroll
    for (int nq = 0; nq < 16; ++nq) {
        uint2 u = Yg[(size_t)nq * E + e];
        int k = 4 * nq;   // unit nq holds features 4nq..4nq+3
        float x0 = bf2f((ushort)(u.x & 0xffffu));
        float x1 = bf2f((ushort)(u.x >> 16));
        float x2 = bf2f((ushort)(u.y & 0xffffu));
        float x3 = bf2f((ushort)(u.y >> 16));
        s = fmaf(sp(ac[k]     * x0 + ac[F + k]),     wsh[k],     s);
        s = fmaf(sp(ac[k + 1] * x1 + ac[F + k + 1]), wsh[k + 1], s);
        s = fmaf(sp(ac[k + 2] * x2 + ac[F + k + 2]), wsh[k + 2], s);
        s = fmaf(sp(ac[k + 3] * x3 + ac[F + k + 3]), wsh[k + 3], s);
    }
    s_out[e] = s;
}

// Gather/scatter only: edge direction + scaled scatter-add. Isolated so the
// atomic write-through drain doesn't stall the streaming softplus pass.
__global__ __launch_bounds__(TPB)
void force_kernel(const float* __restrict__ s_in,
                  const float* __restrict__ nbr_shift, const float* __restrict__ pos,
                  const int* __restrict__ edge_index, float* __restrict__ out, int E)
{
    const long e = (long)blockIdx.x * TPB + threadIdx.x;
    if (e >= E) return;

    const int jn  = edge_index[e];        // source
    const int in_ = edge_index[E + e];    // target
    float dx = pos[3 * in_ + 0] + nbr_shift[3 * e + 0] - pos[3 * jn + 0];
    float dy = pos[3 * in_ + 1] + nbr_shift[3 * e + 1] - pos[3 * jn + 1];
    float dz = pos[3 * in_ + 2] + nbr_shift[3 * e + 2] - pos[3 * jn + 2];
    float inv = rsqrtf(dx * dx + dy * dy + dz * dz);
    float fs = s_in[e] * inv;
    unsafeAtomicAdd(&out[3 * in_ + 0], fs * dx);
    unsafeAtomicAdd(&out[3 * in_ + 1], fs * dy);
    unsafeAtomicAdd(&out[3 * in_ + 2], fs * dz);
}

extern "C" void kernel_launch(void* const* d_in, const int* in_sizes, int n_in,
                              void* d_out, int out_size, void* d_ws, size_t ws_size,
                              hipStream_t stream)
{
    const int E = in_sizes[0] / F;                 // 1,600,000 (divisible by 256)
    const float* edge_attr = (const float*)d_in[0];
    const float* nbr_shift = (const float*)d_in[1];
    const float* pos       = (const float*)d_in[2];
    const float* Ws        = (const float*)d_in[3];   // [3][64][64]
    // d_in[4] (bs) unused: Linear bias cancels under BatchNorm
    const float* gammas    = (const float*)d_in[5];
    const float* betas     = (const float*)d_in[6];
    const float* w_out     = (const float*)d_in[7];
    const float* b_out     = (const float*)d_in[8];
    const int*   edge_index= (const int*)d_in[9];     // [2][E] int32

    uint2* Y1 = (uint2*)d_ws;                                  // E*64 bf16 blocked
    uint2* Y2 = (uint2*)((char*)d_ws + (size_t)E * F * 2);
    float* stats = (float*)((char*)d_ws + (size_t)E * F * 4);  // 6*64 fp32
    float* s_buf = (float*)((char*)d_ws + (size_t)E * F * 4 + 4096);  // E fp32

    hipMemsetAsync(stats, 0, 6 * F * sizeof(float), stream);
    hipMemsetAsync(d_out, 0, (size_t)out_size * sizeof(float), stream);

    layer_mfma<0><<<LGRID, TPB, 0, stream>>>(edge_attr, Y1, Ws,
                                             nullptr, nullptr, nullptr, stats, E);
    layer_mfma<1><<<LGRID, TPB, 0, stream>>>(Y1, Y2, Ws + F * F,
                                             stats, gammas, betas, stats + 2 * F, E);
    layer_mfma<1><<<LGRID, TPB, 0, stream>>>(Y2, Y1, Ws + 2 * F * F,
                                             stats + 2 * F, gammas + F, betas + F,
                                             stats + 4 * F, E);
    s_kernel<<<E / TPB, TPB, 0, stream>>>(Y1, stats + 4 * F, gammas + 2 * F,
                                          betas + 2 * F, w_out, b_out, s_buf, E);
    force_kernel<<<E / TPB, TPB, 0, stream>>>(s_buf, nbr_shift, pos, edge_index,
                                              (float*)d_out, E);
}

// Round 2
// 1037.220 us; speedup vs baseline: 1.1912x; 1.0309x over previous
//
#include <hip/hip_runtime.h>
#include <hip/hip_bf16.h>
#include <math.h>

#define F 64
#define TPB 256
#define MTILE 256          // edges per tile (4 waves x 64)
#define BN_EPS 1e-5f
#define LGRID 512          // persistent blocks for layer kernels (2/CU)
#define NREP 8             // one force-accumulator replica per XCD

typedef __attribute__((ext_vector_type(8))) short short8;   // 8 bf16 (4 VGPRs)
typedef __attribute__((ext_vector_type(4))) float f32x4;

__device__ __forceinline__ float sp(float x) {
    // stable softplus = max(x,0) + log1p(exp(-|x|))
    return fmaxf(x, 0.f) + __logf(1.f + __expf(-fabsf(x)));
}
__device__ __forceinline__ ushort f2bf(float f) {
    __hip_bfloat16 h = __float2bfloat16(f);
    return *reinterpret_cast<ushort*>(&h);
}
__device__ __forceinline__ float bf2f(ushort u) {
    unsigned v = ((unsigned)u) << 16;
    return __builtin_bit_cast(float, v);
}

// One dense layer via MFMA, persistent-block version.
// - grid-stride over 256-edge tiles; W^T staged to LDS once per block
// - BN stats accumulated in registers across tiles, reduced once at end
// - HAS_ACT path: TRUE double-buffered staging regs (xbA/xbB) so next-tile
//   loads issue BEFORE the current convert (no WAR serialization); bfr is
//   per-mi (2 frags) to keep VGPRs under the 2-block/CU cap.
// - layer 1 (fp32 input, 64-VGPR staging) stays single-buffered.
// - Linear bias DROPPED: bias cancels under BatchNorm.
template <int HAS_ACT>
__global__ __launch_bounds__(TPB, 2)
void layer_mfma(const void* __restrict__ Xv, uint2* __restrict__ Yg,
                const float* __restrict__ W,
                const float* __restrict__ prev_stats,
                const float* __restrict__ gamma_prev,
                const float* __restrict__ beta_prev,
                float* __restrict__ stats_out, int E)
{
    __shared__ short8 Wt[512];        // W^T blocked: unit(kq,n)=kq*64+n, 8 KB
    __shared__ float aca[F], acb[F];  // BN affine a, c (prev layer)
    __shared__ float sh_s[F], sh_q[F];

    const int t  = threadIdx.x;
    const int w  = t >> 6;        // wave 0..3  (m-range)
    const int l  = t & 63;        // lane
    const int ln = l & 15;
    const int q  = l >> 4;        // quad

    // ---- stage W^T (bf16, blocked by k-groups of 8) — once per block ----
    #pragma unroll
    for (int uu = 0; uu < 2; ++uu) {
        int u = t + uu * 256;
        int kq = u >> 6, n = u & 63;
        short8 pk;
        #pragma unroll
        for (int j = 0; j < 8; ++j)
            pk[j] = (short)f2bf(W[(kq * 8 + j) * F + n]);
        Wt[u] = pk;
    }
    if (t < F) {
        sh_s[t] = 0.f; sh_q[t] = 0.f;
        if (HAS_ACT) {
            float inv_e = 1.f / (float)E;
            float mu = prev_stats[t] * inv_e;
            float var = prev_stats[F + t] * inv_e - mu * mu;
            float a = gamma_prev[t] * rsqrtf(var + BN_EPS);
            aca[t] = a;
            acb[t] = beta_prev[t] - mu * a;
        }
    }
    __syncthreads();

    // A-frags (W^T): lane holds W[k=32ks+8q+j][n=ni*16+ln]
    short8 afr[4][2];
    #pragma unroll
    for (int ni = 0; ni < 4; ++ni)
        #pragma unroll
        for (int ks = 0; ks < 2; ++ks)
            afr[ni][ks] = Wt[(4 * ks + q) * 64 + ni * 16 + ln];

    // per-thread BN stats accumulators, persist across tiles
    float ps[16], pq[16];
    #pragma unroll
    for (int p = 0; p < 16; ++p) { ps[p] = 0.f; pq[p] = 0.f; }

    const int ntiles = E >> 8;   // E / MTILE

    // store (packed 4-feature units, coalesced) + stats accumulate
    auto store_acc = [&](f32x4 (&acc)[4][4], int tt) {
        const long e0 = (long)tt * MTILE + w * 64;
        #pragma unroll
        for (int ni = 0; ni < 4; ++ni)
            #pragma unroll
            for (int mi = 0; mi < 4; ++mi) {
                const long e = e0 + mi * 16 + ln;
                f32x4 v = acc[ni][mi];
                uint2 u;
                u.x = (uint)f2bf(v[0]) | ((uint)f2bf(v[1]) << 16);
                u.y = (uint)f2bf(v[2]) | ((uint)f2bf(v[3]) << 16);
                Yg[(size_t)(ni * 4 + q) * E + e] = u;
                #pragma unroll
                for (int r = 0; r < 4; ++r) {
                    float x = v[r];
                    ps[ni * 4 + r] += x;
                    pq[ni * 4 + r] = fmaf(x, x, pq[ni * 4 + r]);
                }
            }
    };

    if constexpr (HAS_ACT) {
        const uint2* X = (const uint2*)Xv;
        uint2 xbA[4][2][2], xbB[4][2][2];   // double-buffered staging

        auto load = [&](uint2 (&xb)[4][2][2], int tt) {
            const long eb = (long)tt * MTILE + w * 64;
            #pragma unroll
            for (int mi = 0; mi < 4; ++mi) {
                const long e = eb + mi * 16 + ln;
                #pragma unroll
                for (int ks = 0; ks < 2; ++ks) {
                    xb[mi][ks][0] = X[(size_t)(8 * ks + 2 * q) * E + e];
                    xb[mi][ks][1] = X[(size_t)(8 * ks + 2 * q + 1) * E + e];
                }
            }
        };

        auto process = [&](uint2 (&xb)[4][2][2], int tt) {
            f32x4 acc[4][4];
            #pragma unroll
            for (int ni = 0; ni < 4; ++ni)
                #pragma unroll
                for (int mi = 0; mi < 4; ++mi)
                    acc[ni][mi] = (f32x4){0.f, 0.f, 0.f, 0.f};

            #pragma unroll
            for (int mi = 0; mi < 4; ++mi) {
                short8 bfr[2];
                #pragma unroll
                for (int ks = 0; ks < 2; ++ks) {
                    uint vs[4] = {xb[mi][ks][0].x, xb[mi][ks][0].y,
                                  xb[mi][ks][1].x, xb[mi][ks][1].y};
                    short8 b;
                    #pragma unroll
                    for (int d = 0; d < 4; ++d) {
                        // k-index of element 2d: 32ks + 8q + 2d
                        float x0 = bf2f((ushort)(vs[d] & 0xffffu));
                        float x1 = bf2f((ushort)(vs[d] >> 16));
                        int k0 = 32 * ks + 8 * q + 2 * d;
                        b[2*d]   = (short)f2bf(sp(aca[k0]     * x0 + acb[k0]));
                        b[2*d+1] = (short)f2bf(sp(aca[k0 + 1] * x1 + acb[k0 + 1]));
                    }
                    bfr[ks] = b;
                }
                #pragma unroll
                for (int ks = 0; ks < 2; ++ks)
                    #pragma unroll
                    for (int ni = 0; ni < 4; ++ni)
                        acc[ni][mi] = __builtin_amdgcn_mfma_f32_16x16x32_bf16(
                                          afr[ni][ks], bfr[ks], acc[ni][mi], 0, 0, 0);
            }
            store_acc(acc, tt);
        };

        // ping-pong: loads for the next tile always issue a full tile of
        // compute ahead of their consumption.
        int tile = blockIdx.x;
        load(xbA, tile);
        while (true) {
            const int tB = tile + LGRID;
            const bool haveB = tB < ntiles;
            if (haveB) load(xbB, tB);
            process(xbA, tile);
            if (!haveB) break;
            tile = tB + LGRID;
            if (tile < ntiles) load(xbA, tile);
            process(xbB, tB);
            if (tile >= ntiles) break;
        }
    } else {
        const float4* X4 = (const float4*)Xv;
        float4 xb[4][2][2];   // fp32 staging (64 VGPR) — single-buffered

        auto load = [&](int tt) {
            const long eb = (long)tt * MTILE + w * 64;
            #pragma unroll
            for (int mi = 0; mi < 4; ++mi) {
                const long e = eb + mi * 16 + ln;
                #pragma unroll
                for (int ks = 0; ks < 2; ++ks) {
                    xb[mi][ks][0] = X4[(size_t)e * 16 + 8 * ks + 2 * q];
                    xb[mi][ks][1] = X4[(size_t)e * 16 + 8 * ks + 2 * q + 1];
                }
            }
        };

        load(blockIdx.x);
        #pragma unroll 1
        for (int tile = blockIdx.x; tile < ntiles; tile += LGRID) {
            // convert all frags first (frees xb), then prefetch, then MFMA
            short8 bfr[4][2];
            #pragma unroll
            for (int mi = 0; mi < 4; ++mi)
                #pragma unroll
                for (int ks = 0; ks < 2; ++ks) {
                    float4 f0 = xb[mi][ks][0], f1 = xb[mi][ks][1];
                    short8 b;
                    b[0] = (short)f2bf(f0.x); b[1] = (short)f2bf(f0.y);
                    b[2] = (short)f2bf(f0.z); b[3] = (short)f2bf(f0.w);
                    b[4] = (short)f2bf(f1.x); b[5] = (short)f2bf(f1.y);
                    b[6] = (short)f2bf(f1.z); b[7] = (short)f2bf(f1.w);
                    bfr[mi][ks] = b;
                }
            if (tile + LGRID < ntiles) load(tile + LGRID);

            f32x4 acc[4][4];
            #pragma unroll
            for (int ni = 0; ni < 4; ++ni)
                #pragma unroll
                for (int mi = 0; mi < 4; ++mi)
                    acc[ni][mi] = (f32x4){0.f, 0.f, 0.f, 0.f};
            #pragma unroll
            for (int mi = 0; mi < 4; ++mi)
                #pragma unroll
                for (int ks = 0; ks < 2; ++ks)
                    #pragma unroll
                    for (int ni = 0; ni < 4; ++ni)
                        acc[ni][mi] = __builtin_amdgcn_mfma_f32_16x16x32_bf16(
                                          afr[ni][ks], bfr[mi][ks], acc[ni][mi], 0, 0, 0);
            store_acc(acc, tile);
        }
    }

    // ---- stats reduction: once per block ----
    #pragma unroll
    for (int p = 0; p < 16; ++p) {
        #pragma unroll
        for (int m = 1; m < 16; m <<= 1) {
            ps[p] += __shfl_xor(ps[p], m);
            pq[p] += __shfl_xor(pq[p], m);
        }
    }
    if (ln == 0) {
        #pragma unroll
        for (int p = 0; p < 16; ++p) {
            int n = (p >> 2) * 16 + q * 4 + (p & 3);
            atomicAdd(&sh_s[n], ps[p]);
            atomicAdd(&sh_q[n], pq[p]);
        }
    }
    __syncthreads();
    if (t < F) {
        unsafeAtomicAdd(&stats_out[t], sh_s[t]);
        unsafeAtomicAdd(&stats_out[F + t], sh_q[t]);
    }
}

// Fused: s = softplus(a*Y3 + c)·w_out + b_out; force_e = s * dir;
// scatter-add into an XCD-local replica (blockIdx&7 matches the round-robin
// block->XCD dispatch) so atomic cache lines stay in one XCD's L2 instead of
// ping-ponging across all 8 coherence domains.
__global__ __launch_bounds__(TPB)
void force_kernel(const uint2* __restrict__ Yg, const float* __restrict__ stats,
                  const float* __restrict__ gamma, const float* __restrict__ beta,
                  const float* __restrict__ w_out, const float* __restrict__ b_out,
                  const float* __restrict__ nbr_shift, const float* __restrict__ pos,
                  const int* __restrict__ edge_index, float* __restrict__ rep,
                  int E, int nodes3)
{
    __shared__ float ac[2 * F];
    __shared__ float wsh[F];
    const int t = threadIdx.x;
    if (t < F) {
        float inv_e = 1.f / (float)E;
        float mu = stats[t] * inv_e;
        float var = stats[F + t] * inv_e - mu * mu;
        float a = gamma[t] * rsqrtf(var + BN_EPS);
        ac[t] = a;
        ac[F + t] = beta[t] - mu * a;
        wsh[t] = w_out[t];
    }
    __syncthreads();

    const long e = (long)blockIdx.x * TPB + t;
    if (e >= E) return;

    float s = b_out[0];
    #pragma unroll
    for (int nq = 0; nq < 16; ++nq) {
        uint2 u = Yg[(size_t)nq * E + e];
        int k = 4 * nq;   // unit nq holds features 4nq..4nq+3
        float x0 = bf2f((ushort)(u.x & 0xffffu));
        float x1 = bf2f((ushort)(u.x >> 16));
        float x2 = bf2f((ushort)(u.y & 0xffffu));
        float x3 = bf2f((ushort)(u.y >> 16));
        s = fmaf(sp(ac[k]     * x0 + ac[F + k]),     wsh[k],     s);
        s = fmaf(sp(ac[k + 1] * x1 + ac[F + k + 1]), wsh[k + 1], s);
        s = fmaf(sp(ac[k + 2] * x2 + ac[F + k + 2]), wsh[k + 2], s);
        s = fmaf(sp(ac[k + 3] * x3 + ac[F + k + 3]), wsh[k + 3], s);
    }

    const int jn  = edge_index[e];        // source
    const int in_ = edge_index[E + e];    // target
    float dx = pos[3 * in_ + 0] + nbr_shift[3 * e + 0] - pos[3 * jn + 0];
    float dy = pos[3 * in_ + 1] + nbr_shift[3 * e + 1] - pos[3 * jn + 1];
    float dz = pos[3 * in_ + 2] + nbr_shift[3 * e + 2] - pos[3 * jn + 2];
    float inv = rsqrtf(dx * dx + dy * dy + dz * dz);
    float fs = s * inv;

    float* myrep = rep + (size_t)(blockIdx.x & (NREP - 1)) * nodes3;
    unsafeAtomicAdd(&myrep[3 * in_ + 0], fs * dx);
    unsafeAtomicAdd(&myrep[3 * in_ + 1], fs * dy);
    unsafeAtomicAdd(&myrep[3 * in_ + 2], fs * dz);
}

// Sum the 8 replicas into the real output (coalesced, non-atomic).
__global__ __launch_bounds__(TPB)
void reduce_out(const float* __restrict__ rep, float* __restrict__ out, int nodes3)
{
    const int i = blockIdx.x * TPB + threadIdx.x;
    if (i >= nodes3) return;
    float s = 0.f;
    #pragma unroll
    for (int r = 0; r < NREP; ++r)
        s += rep[(size_t)r * nodes3 + i];
    out[i] = s;
}

extern "C" void kernel_launch(void* const* d_in, const int* in_sizes, int n_in,
                              void* d_out, int out_size, void* d_ws, size_t ws_size,
                              hipStream_t stream)
{
    const int E = in_sizes[0] / F;                 // 1,600,000 (divisible by 256)
    const float* edge_attr = (const float*)d_in[0];
    const float* nbr_shift = (const float*)d_in[1];
    const float* pos       = (const float*)d_in[2];
    const float* Ws        = (const float*)d_in[3];   // [3][64][64]
    // d_in[4] (bs) unused: Linear bias cancels under BatchNorm
    const float* gammas    = (const float*)d_in[5];
    const float* betas     = (const float*)d_in[6];
    const float* w_out     = (const float*)d_in[7];
    const float* b_out     = (const float*)d_in[8];
    const int*   edge_index= (const int*)d_in[9];     // [2][E] int32

    uint2* Y1 = (uint2*)d_ws;                                  // E*64 bf16 blocked
    uint2* Y2 = (uint2*)((char*)d_ws + (size_t)E * F * 2);
    float* stats = (float*)((char*)d_ws + (size_t)E * F * 4);  // 6*64 fp32
    float* rep   = (float*)((char*)d_ws + (size_t)E * F * 4 + 4096);  // 8 x nodes3

    hipMemsetAsync(stats, 0, 6 * F * sizeof(float), stream);
    hipMemsetAsync(rep, 0, (size_t)NREP * out_size * sizeof(float), stream);

    layer_mfma<0><<<LGRID, TPB, 0, stream>>>(edge_attr, Y1, Ws,
                                             nullptr, nullptr, nullptr, stats, E);
    layer_mfma<1><<<LGRID, TPB, 0, stream>>>(Y1, Y2, Ws + F * F,
                                             stats, gammas, betas, stats + 2 * F, E);
    layer_mfma<1><<<LGRID, TPB, 0, stream>>>(Y2, Y1, Ws + 2 * F * F,
                                             stats + 2 * F, gammas + F, betas + F,
                                             stats + 4 * F, E);
    force_kernel<<<E / TPB, TPB, 0, stream>>>(Y1, stats + 4 * F, gammas + 2 * F,
                                              betas + 2 * F, w_out, b_out,
                                              nbr_shift, pos, edge_index, rep,
                                              E, out_size);
    reduce_out<<<(out_size + TPB - 1) / TPB, TPB, 0, stream>>>(rep, (float*)d_out,
                                                               out_size);
}

// Round 3
// 924.594 us; speedup vs baseline: 1.3363x; 1.1218x over previous
//
#include <hip/hip_runtime.h>
#include <hip/hip_bf16.h>
#include <math.h>

#define F 64
#define TPB 256
#define MTILE 256          // edges per tile (4 waves x 64)
#define BN_EPS 1e-5f
#define LGRID 512          // persistent blocks for layer kernels (2/CU)

#define NB 16              // node-range buckets (50000/16 = 3125 nodes each)
#define RMAX 3136          // max nodes per bucket (padded)
#define CAP 114688         // record capacity per bucket (mean 100k, +48 sigma)
#define BPB 16             // accumulate blocks per bucket
#define SLABSTRIDE (3 * RMAX)   // floats per slab

typedef __attribute__((ext_vector_type(8))) short short8;   // 8 bf16 (4 VGPRs)
typedef __attribute__((ext_vector_type(4))) float f32x4;

__device__ __forceinline__ float sp(float x) {
    // stable softplus = max(x,0) + log1p(exp(-|x|))
    return fmaxf(x, 0.f) + __logf(1.f + __expf(-fabsf(x)));
}
__device__ __forceinline__ ushort f2bf(float f) {
    __hip_bfloat16 h = __float2bfloat16(f);
    return *reinterpret_cast<ushort*>(&h);
}
__device__ __forceinline__ float bf2f(ushort u) {
    unsigned v = ((unsigned)u) << 16;
    return __builtin_bit_cast(float, v);
}

// One dense layer via MFMA, persistent-block version (unchanged from R1).
template <int HAS_ACT>
__global__ __launch_bounds__(TPB, 2)
void layer_mfma(const void* __restrict__ Xv, uint2* __restrict__ Yg,
                const float* __restrict__ W,
                const float* __restrict__ prev_stats,
                const float* __restrict__ gamma_prev,
                const float* __restrict__ beta_prev,
                float* __restrict__ stats_out, int E)
{
    __shared__ short8 Wt[512];        // W^T blocked: unit(kq,n)=kq*64+n, 8 KB
    __shared__ float aca[F], acb[F];  // BN affine a, c (prev layer)
    __shared__ float sh_s[F], sh_q[F];

    const int t  = threadIdx.x;
    const int w  = t >> 6;        // wave 0..3  (m-range)
    const int l  = t & 63;        // lane
    const int ln = l & 15;
    const int q  = l >> 4;        // quad

    #pragma unroll
    for (int uu = 0; uu < 2; ++uu) {
        int u = t + uu * 256;
        int kq = u >> 6, n = u & 63;
        short8 pk;
        #pragma unroll
        for (int j = 0; j < 8; ++j)
            pk[j] = (short)f2bf(W[(kq * 8 + j) * F + n]);
        Wt[u] = pk;
    }
    if (t < F) {
        sh_s[t] = 0.f; sh_q[t] = 0.f;
        if (HAS_ACT) {
            float inv_e = 1.f / (float)E;
            float mu = prev_stats[t] * inv_e;
            float var = prev_stats[F + t] * inv_e - mu * mu;
            float a = gamma_prev[t] * rsqrtf(var + BN_EPS);
            aca[t] = a;
            acb[t] = beta_prev[t] - mu * a;
        }
    }
    __syncthreads();

    short8 afr[4][2];
    #pragma unroll
    for (int ni = 0; ni < 4; ++ni)
        #pragma unroll
        for (int ks = 0; ks < 2; ++ks)
            afr[ni][ks] = Wt[(4 * ks + q) * 64 + ni * 16 + ln];

    float ps[16], pq[16];
    #pragma unroll
    for (int p = 0; p < 16; ++p) { ps[p] = 0.f; pq[p] = 0.f; }

    const int ntiles = E >> 8;   // E / MTILE

    auto store_acc = [&](f32x4 (&acc)[4][4], int tt) {
        const long e0 = (long)tt * MTILE + w * 64;
        #pragma unroll
        for (int ni = 0; ni < 4; ++ni)
            #pragma unroll
            for (int mi = 0; mi < 4; ++mi) {
                const long e = e0 + mi * 16 + ln;
                f32x4 v = acc[ni][mi];
                uint2 u;
                u.x = (uint)f2bf(v[0]) | ((uint)f2bf(v[1]) << 16);
                u.y = (uint)f2bf(v[2]) | ((uint)f2bf(v[3]) << 16);
                Yg[(size_t)(ni * 4 + q) * E + e] = u;
                #pragma unroll
                for (int r = 0; r < 4; ++r) {
                    float x = v[r];
                    ps[ni * 4 + r] += x;
                    pq[ni * 4 + r] = fmaf(x, x, pq[ni * 4 + r]);
                }
            }
    };

    if constexpr (HAS_ACT) {
        const uint2* X = (const uint2*)Xv;
        uint2 xbA[4][2][2], xbB[4][2][2];   // double-buffered staging

        auto load = [&](uint2 (&xb)[4][2][2], int tt) {
            const long eb = (long)tt * MTILE + w * 64;
            #pragma unroll
            for (int mi = 0; mi < 4; ++mi) {
                const long e = eb + mi * 16 + ln;
                #pragma unroll
                for (int ks = 0; ks < 2; ++ks) {
                    xb[mi][ks][0] = X[(size_t)(8 * ks + 2 * q) * E + e];
                    xb[mi][ks][1] = X[(size_t)(8 * ks + 2 * q + 1) * E + e];
                }
            }
        };

        auto process = [&](uint2 (&xb)[4][2][2], int tt) {
            f32x4 acc[4][4];
            #pragma unroll
            for (int ni = 0; ni < 4; ++ni)
                #pragma unroll
                for (int mi = 0; mi < 4; ++mi)
                    acc[ni][mi] = (f32x4){0.f, 0.f, 0.f, 0.f};

            #pragma unroll
            for (int mi = 0; mi < 4; ++mi) {
                short8 bfr[2];
                #pragma unroll
                for (int ks = 0; ks < 2; ++ks) {
                    uint vs[4] = {xb[mi][ks][0].x, xb[mi][ks][0].y,
                                  xb[mi][ks][1].x, xb[mi][ks][1].y};
                    short8 b;
                    #pragma unroll
                    for (int d = 0; d < 4; ++d) {
                        float x0 = bf2f((ushort)(vs[d] & 0xffffu));
                        float x1 = bf2f((ushort)(vs[d] >> 16));
                        int k0 = 32 * ks + 8 * q + 2 * d;
                        b[2*d]   = (short)f2bf(sp(aca[k0]     * x0 + acb[k0]));
                        b[2*d+1] = (short)f2bf(sp(aca[k0 + 1] * x1 + acb[k0 + 1]));
                    }
                    bfr[ks] = b;
                }
                #pragma unroll
                for (int ks = 0; ks < 2; ++ks)
                    #pragma unroll
                    for (int ni = 0; ni < 4; ++ni)
                        acc[ni][mi] = __builtin_amdgcn_mfma_f32_16x16x32_bf16(
                                          afr[ni][ks], bfr[ks], acc[ni][mi], 0, 0, 0);
            }
            store_acc(acc, tt);
        };

        int tile = blockIdx.x;
        load(xbA, tile);
        while (true) {
            const int tB = tile + LGRID;
            const bool haveB = tB < ntiles;
            if (haveB) load(xbB, tB);
            process(xbA, tile);
            if (!haveB) break;
            tile = tB + LGRID;
            if (tile < ntiles) load(xbA, tile);
            process(xbB, tB);
            if (tile >= ntiles) break;
        }
    } else {
        const float4* X4 = (const float4*)Xv;
        float4 xb[4][2][2];   // fp32 staging (64 VGPR) — single-buffered

        auto load = [&](int tt) {
            const long eb = (long)tt * MTILE + w * 64;
            #pragma unroll
            for (int mi = 0; mi < 4; ++mi) {
                const long e = eb + mi * 16 + ln;
                #pragma unroll
                for (int ks = 0; ks < 2; ++ks) {
                    xb[mi][ks][0] = X4[(size_t)e * 16 + 8 * ks + 2 * q];
                    xb[mi][ks][1] = X4[(size_t)e * 16 + 8 * ks + 2 * q + 1];
                }
            }
        };

        load(blockIdx.x);
        #pragma unroll 1
        for (int tile = blockIdx.x; tile < ntiles; tile += LGRID) {
            short8 bfr[4][2];
            #pragma unroll
            for (int mi = 0; mi < 4; ++mi)
                #pragma unroll
                for (int ks = 0; ks < 2; ++ks) {
                    float4 f0 = xb[mi][ks][0], f1 = xb[mi][ks][1];
                    short8 b;
                    b[0] = (short)f2bf(f0.x); b[1] = (short)f2bf(f0.y);
                    b[2] = (short)f2bf(f0.z); b[3] = (short)f2bf(f0.w);
                    b[4] = (short)f2bf(f1.x); b[5] = (short)f2bf(f1.y);
                    b[6] = (short)f2bf(f1.z); b[7] = (short)f2bf(f1.w);
                    bfr[mi][ks] = b;
                }
            if (tile + LGRID < ntiles) load(tile + LGRID);

            f32x4 acc[4][4];
            #pragma unroll
            for (int ni = 0; ni < 4; ++ni)
                #pragma unroll
                for (int mi = 0; mi < 4; ++mi)
                    acc[ni][mi] = (f32x4){0.f, 0.f, 0.f, 0.f};
            #pragma unroll
            for (int mi = 0; mi < 4; ++mi)
                #pragma unroll
                for (int ks = 0; ks < 2; ++ks)
                    #pragma unroll
                    for (int ni = 0; ni < 4; ++ni)
                        acc[ni][mi] = __builtin_amdgcn_mfma_f32_16x16x32_bf16(
                                          afr[ni][ks], bfr[mi][ks], acc[ni][mi], 0, 0, 0);
            store_acc(acc, tile);
        }
    }

    #pragma unroll
    for (int p = 0; p < 16; ++p) {
        #pragma unroll
        for (int m = 1; m < 16; m <<= 1) {
            ps[p] += __shfl_xor(ps[p], m);
            pq[p] += __shfl_xor(pq[p], m);
        }
    }
    if (ln == 0) {
        #pragma unroll
        for (int p = 0; p < 16; ++p) {
            int n = (p >> 2) * 16 + q * 4 + (p & 3);
            atomicAdd(&sh_s[n], ps[p]);
            atomicAdd(&sh_q[n], pq[p]);
        }
    }
    __syncthreads();
    if (t < F) {
        unsafeAtomicAdd(&stats_out[t], sh_s[t]);
        unsafeAtomicAdd(&stats_out[F + t], sh_q[t]);
    }
}

// Fused s + force, emitting (fx,fy,fz,target) records into NB node-range
// buckets instead of doing 3 device-scope atomics per edge (those execute at
// the cross-XCD coherence point at ~18 G/s — the old 270 us bottleneck).
// Reservation: one int atomic per bucket per block (100k total, not 4.8M).
__global__ __launch_bounds__(TPB)
void force_bucket(const uint2* __restrict__ Yg, const float* __restrict__ stats,
                  const float* __restrict__ gamma, const float* __restrict__ beta,
                  const float* __restrict__ w_out, const float* __restrict__ b_out,
                  const float* __restrict__ nbr_shift, const float* __restrict__ pos,
                  const int* __restrict__ edge_index,
                  float4* __restrict__ recs, int* __restrict__ gcnt,
                  float* __restrict__ spill, int E, int R)
{
    __shared__ float ac[2 * F];
    __shared__ float wsh[F];
    __shared__ int lcnt[NB], lbase[NB];
    const int t = threadIdx.x;
    if (t < F) {
        float inv_e = 1.f / (float)E;
        float mu = stats[t] * inv_e;
        float var = stats[F + t] * inv_e - mu * mu;
        float a = gamma[t] * rsqrtf(var + BN_EPS);
        ac[t] = a;
        ac[F + t] = beta[t] - mu * a;
        wsh[t] = w_out[t];
    }
    if (t < NB) lcnt[t] = 0;
    __syncthreads();

    const long e = (long)blockIdx.x * TPB + t;
    const bool valid = e < E;
    float4 rec;
    int b = 0, lrank = 0, in_ = 0;

    if (valid) {
        float s = b_out[0];
        #pragma unroll
        for (int nq = 0; nq < 16; ++nq) {
            uint2 u = Yg[(size_t)nq * E + e];
            int k = 4 * nq;
            float x0 = bf2f((ushort)(u.x & 0xffffu));
            float x1 = bf2f((ushort)(u.x >> 16));
            float x2 = bf2f((ushort)(u.y & 0xffffu));
            float x3 = bf2f((ushort)(u.y >> 16));
            s = fmaf(sp(ac[k]     * x0 + ac[F + k]),     wsh[k],     s);
            s = fmaf(sp(ac[k + 1] * x1 + ac[F + k + 1]), wsh[k + 1], s);
            s = fmaf(sp(ac[k + 2] * x2 + ac[F + k + 2]), wsh[k + 2], s);
            s = fmaf(sp(ac[k + 3] * x3 + ac[F + k + 3]), wsh[k + 3], s);
        }

        const int jn = edge_index[e];       // source
        in_ = edge_index[E + e];            // target
        float dx = pos[3 * in_ + 0] + nbr_shift[3 * e + 0] - pos[3 * jn + 0];
        float dy = pos[3 * in_ + 1] + nbr_shift[3 * e + 1] - pos[3 * jn + 1];
        float dz = pos[3 * in_ + 2] + nbr_shift[3 * e + 2] - pos[3 * jn + 2];
        float inv = rsqrtf(dx * dx + dy * dy + dz * dz);
        float fs = s * inv;
        rec.x = fs * dx; rec.y = fs * dy; rec.z = fs * dz;
        rec.w = __int_as_float(in_);

        b = (int)((unsigned)in_ / (unsigned)R);
        lrank = atomicAdd(&lcnt[b], 1);     // LDS rank within block's bucket
    }
    __syncthreads();
    if (t < NB) lbase[t] = atomicAdd(&gcnt[t], lcnt[t]);   // reserve
    __syncthreads();
    if (valid) {
        int idx = lbase[b] + lrank;
        if (idx < CAP) {
            recs[(size_t)b * CAP + idx] = rec;
        } else {   // statistically unreachable overflow fallback
            unsafeAtomicAdd(&spill[3 * in_ + 0], rec.x);
            unsafeAtomicAdd(&spill[3 * in_ + 1], rec.y);
            unsafeAtomicAdd(&spill[3 * in_ + 2], rec.z);
        }
    }
}

// Per-bucket LDS accumulation: BPB blocks grid-stride one bucket's records,
// ds_add_f32 into a 3*R-float LDS accumulator, write slab coalesced.
// Zero device-scope atomics.
__global__ __launch_bounds__(TPB)
void bucket_accum(const float4* __restrict__ recs, const int* __restrict__ gcnt,
                  float* __restrict__ slabs, int R)
{
    __shared__ float acc[SLABSTRIDE];
    const int bucket = blockIdx.x / BPB;
    const int sub    = blockIdx.x - bucket * BPB;
    const int t = threadIdx.x;
    const int len = 3 * R;

    for (int i = t; i < len; i += TPB) acc[i] = 0.f;
    __syncthreads();

    int cnt = gcnt[bucket];
    if (cnt > CAP) cnt = CAP;
    const int nbase = bucket * R;
    const float4* rb = recs + (size_t)bucket * CAP;

    for (int i = sub * TPB + t; i < cnt; i += BPB * TPB) {
        float4 r = rb[i];
        int loc = 3 * (__float_as_int(r.w) - nbase);
        atomicAdd(&acc[loc + 0], r.x);
        atomicAdd(&acc[loc + 1], r.y);
        atomicAdd(&acc[loc + 2], r.z);
    }
    __syncthreads();

    float* out = slabs + (size_t)blockIdx.x * SLABSTRIDE;
    for (int i = t; i < len; i += TPB) out[i] = acc[i];
}

// out[i] = sum over BPB slabs of this node's bucket + spill.
__global__ __launch_bounds__(TPB)
void reduce_out(const float* __restrict__ slabs, const float* __restrict__ spill,
                float* __restrict__ out, int nodes3, int R)
{
    const int i = blockIdx.x * TPB + threadIdx.x;
    if (i >= nodes3) return;
    const int node = i / 3, c = i - 3 * node;
    const int bucket = node / R, loc = node - bucket * R;
    const size_t off = (size_t)(bucket * BPB) * SLABSTRIDE + 3 * loc + c;
    float s = spill[i];
    #pragma unroll
    for (int r = 0; r < BPB; ++r)
        s += slabs[off + (size_t)r * SLABSTRIDE];
    out[i] = s;
}

extern "C" void kernel_launch(void* const* d_in, const int* in_sizes, int n_in,
                              void* d_out, int out_size, void* d_ws, size_t ws_size,
                              hipStream_t stream)
{
    const int E = in_sizes[0] / F;                 // 1,600,000 (divisible by 256)
    const float* edge_attr = (const float*)d_in[0];
    const float* nbr_shift = (const float*)d_in[1];
    const float* pos       = (const float*)d_in[2];
    const float* Ws        = (const float*)d_in[3];   // [3][64][64]
    // d_in[4] (bs) unused: Linear bias cancels under BatchNorm
    const float* gammas    = (const float*)d_in[5];
    const float* betas     = (const float*)d_in[6];
    const float* w_out     = (const float*)d_in[7];
    const float* b_out     = (const float*)d_in[8];
    const int*   edge_index= (const int*)d_in[9];     // [2][E] int32

    const int nodes3 = out_size;                      // 150000 floats
    const int nodes  = nodes3 / 3;
    const int R = (nodes + NB - 1) / NB;              // 3125

    char* p = (char*)d_ws;
    const size_t SZY = (size_t)E * F * 2;             // 204.8 MB per Y buffer
    uint2* Y1 = (uint2*)p;                 p += SZY;
    uint2* Y2 = (uint2*)p;                 p += SZY;
    float* stats = (float*)p;              p += 4096;
    float4* recs = (float4*)p;             p += (size_t)NB * CAP * 16;
    int*   gcnt  = (int*)p;                p += 256;
    float* slabs = (float*)p;              p += (size_t)NB * BPB * SLABSTRIDE * 4;
    float* spill = (float*)p;              p += (size_t)nodes3 * 4;

    hipMemsetAsync(stats, 0, 6 * F * sizeof(float), stream);
    hipMemsetAsync(gcnt, 0, 256, stream);
    hipMemsetAsync(spill, 0, (size_t)nodes3 * sizeof(float), stream);

    layer_mfma<0><<<LGRID, TPB, 0, stream>>>(edge_attr, Y1, Ws,
                                             nullptr, nullptr, nullptr, stats, E);
    layer_mfma<1><<<LGRID, TPB, 0, stream>>>(Y1, Y2, Ws + F * F,
                                             stats, gammas, betas, stats + 2 * F, E);
    layer_mfma<1><<<LGRID, TPB, 0, stream>>>(Y2, Y1, Ws + 2 * F * F,
                                             stats + 2 * F, gammas + F, betas + F,
                                             stats + 4 * F, E);
    force_bucket<<<(E + TPB - 1) / TPB, TPB, 0, stream>>>(
        Y1, stats + 4 * F, gammas + 2 * F, betas + 2 * F, w_out, b_out,
        nbr_shift, pos, edge_index, recs, gcnt, spill, E, R);
    bucket_accum<<<NB * BPB, TPB, 0, stream>>>(recs, gcnt, slabs, R);
    reduce_out<<<(nodes3 + TPB - 1) / TPB, TPB, 0, stream>>>(
        slabs, spill, (float*)d_out, nodes3, R);
}

// Round 5
// 899.573 us; speedup vs baseline: 1.3735x; 1.0278x over previous
//
#include <hip/hip_runtime.h>
#include <hip/hip_bf16.h>
#include <math.h>

#define F 64
#define TPB 256
#define MTILE 256          // edges per tile (4 waves x 64)
#define BN_EPS 1e-5f
#define LGRID 512          // persistent blocks for layer kernels (2/CU)

#define NB 16              // node-range buckets (50000/16 = 3125 nodes each)
#define RMAX 3136          // max nodes per bucket (padded)
#define BPB 16             // accumulate blocks per bucket
#define SLABSTRIDE (3 * RMAX)   // floats per slab

typedef __attribute__((ext_vector_type(8))) short short8;   // 8 bf16 (4 VGPRs)
typedef __attribute__((ext_vector_type(4))) float f32x4;

__device__ __forceinline__ float sp(float x) {
    // stable softplus = max(x,0) + log1p(exp(-|x|))
    return fmaxf(x, 0.f) + __logf(1.f + __expf(-fabsf(x)));
}
__device__ __forceinline__ ushort f2bf(float f) {
    __hip_bfloat16 h = __float2bfloat16(f);
    return *reinterpret_cast<ushort*>(&h);
}
__device__ __forceinline__ float bf2f(ushort u) {
    unsigned v = ((unsigned)u) << 16;
    return __builtin_bit_cast(float, v);
}

// One dense layer via MFMA, persistent-block version (unchanged from R3).
template <int HAS_ACT>
__global__ __launch_bounds__(TPB, 2)
void layer_mfma(const void* __restrict__ Xv, uint2* __restrict__ Yg,
                const float* __restrict__ W,
                const float* __restrict__ prev_stats,
                const float* __restrict__ gamma_prev,
                const float* __restrict__ beta_prev,
                float* __restrict__ stats_out, int E)
{
    __shared__ short8 Wt[512];        // W^T blocked: unit(kq,n)=kq*64+n, 8 KB
    __shared__ float aca[F], acb[F];  // BN affine a, c (prev layer)
    __shared__ float sh_s[F], sh_q[F];

    const int t  = threadIdx.x;
    const int w  = t >> 6;        // wave 0..3  (m-range)
    const int l  = t & 63;        // lane
    const int ln = l & 15;
    const int q  = l >> 4;        // quad

    #pragma unroll
    for (int uu = 0; uu < 2; ++uu) {
        int u = t + uu * 256;
        int kq = u >> 6, n = u & 63;
        short8 pk;
        #pragma unroll
        for (int j = 0; j < 8; ++j)
            pk[j] = (short)f2bf(W[(kq * 8 + j) * F + n]);
        Wt[u] = pk;
    }
    if (t < F) {
        sh_s[t] = 0.f; sh_q[t] = 0.f;
        if (HAS_ACT) {
            float inv_e = 1.f / (float)E;
            float mu = prev_stats[t] * inv_e;
            float var = prev_stats[F + t] * inv_e - mu * mu;
            float a = gamma_prev[t] * rsqrtf(var + BN_EPS);
            aca[t] = a;
            acb[t] = beta_prev[t] - mu * a;
        }
    }
    __syncthreads();

    short8 afr[4][2];
    #pragma unroll
    for (int ni = 0; ni < 4; ++ni)
        #pragma unroll
        for (int ks = 0; ks < 2; ++ks)
            afr[ni][ks] = Wt[(4 * ks + q) * 64 + ni * 16 + ln];

    float ps[16], pq[16];
    #pragma unroll
    for (int p = 0; p < 16; ++p) { ps[p] = 0.f; pq[p] = 0.f; }

    const int ntiles = E >> 8;   // E / MTILE

    auto store_acc = [&](f32x4 (&acc)[4][4], int tt) {
        const long e0 = (long)tt * MTILE + w * 64;
        #pragma unroll
        for (int ni = 0; ni < 4; ++ni)
            #pragma unroll
            for (int mi = 0; mi < 4; ++mi) {
                const long e = e0 + mi * 16 + ln;
                f32x4 v = acc[ni][mi];
                uint2 u;
                u.x = (uint)f2bf(v[0]) | ((uint)f2bf(v[1]) << 16);
                u.y = (uint)f2bf(v[2]) | ((uint)f2bf(v[3]) << 16);
                Yg[(size_t)(ni * 4 + q) * E + e] = u;
                #pragma unroll
                for (int r = 0; r < 4; ++r) {
                    float x = v[r];
                    ps[ni * 4 + r] += x;
                    pq[ni * 4 + r] = fmaf(x, x, pq[ni * 4 + r]);
                }
            }
    };

    if constexpr (HAS_ACT) {
        const uint2* X = (const uint2*)Xv;
        uint2 xbA[4][2][2], xbB[4][2][2];   // double-buffered staging

        auto load = [&](uint2 (&xb)[4][2][2], int tt) {
            const long eb = (long)tt * MTILE + w * 64;
            #pragma unroll
            for (int mi = 0; mi < 4; ++mi) {
                const long e = eb + mi * 16 + ln;
                #pragma unroll
                for (int ks = 0; ks < 2; ++ks) {
                    xb[mi][ks][0] = X[(size_t)(8 * ks + 2 * q) * E + e];
                    xb[mi][ks][1] = X[(size_t)(8 * ks + 2 * q + 1) * E + e];
                }
            }
        };

        auto process = [&](uint2 (&xb)[4][2][2], int tt) {
            f32x4 acc[4][4];
            #pragma unroll
            for (int ni = 0; ni < 4; ++ni)
                #pragma unroll
                for (int mi = 0; mi < 4; ++mi)
                    acc[ni][mi] = (f32x4){0.f, 0.f, 0.f, 0.f};

            #pragma unroll
            for (int mi = 0; mi < 4; ++mi) {
                short8 bfr[2];
                #pragma unroll
                for (int ks = 0; ks < 2; ++ks) {
                    uint vs[4] = {xb[mi][ks][0].x, xb[mi][ks][0].y,
                                  xb[mi][ks][1].x, xb[mi][ks][1].y};
                    short8 b;
                    #pragma unroll
                    for (int d = 0; d < 4; ++d) {
                        float x0 = bf2f((ushort)(vs[d] & 0xffffu));
                        float x1 = bf2f((ushort)(vs[d] >> 16));
                        int k0 = 32 * ks + 8 * q + 2 * d;
                        b[2*d]   = (short)f2bf(sp(aca[k0]     * x0 + acb[k0]));
                        b[2*d+1] = (short)f2bf(sp(aca[k0 + 1] * x1 + acb[k0 + 1]));
                    }
                    bfr[ks] = b;
                }
                #pragma unroll
                for (int ks = 0; ks < 2; ++ks)
                    #pragma unroll
                    for (int ni = 0; ni < 4; ++ni)
                        acc[ni][mi] = __builtin_amdgcn_mfma_f32_16x16x32_bf16(
                                          afr[ni][ks], bfr[ks], acc[ni][mi], 0, 0, 0);
            }
            store_acc(acc, tt);
        };

        int tile = blockIdx.x;
        load(xbA, tile);
        while (true) {
            const int tB = tile + LGRID;
            const bool haveB = tB < ntiles;
            if (haveB) load(xbB, tB);
            process(xbA, tile);
            if (!haveB) break;
            tile = tB + LGRID;
            if (tile < ntiles) load(xbA, tile);
            process(xbB, tB);
            if (tile >= ntiles) break;
        }
    } else {
        const float4* X4 = (const float4*)Xv;
        float4 xb[4][2][2];   // fp32 staging (64 VGPR) — single-buffered

        auto load = [&](int tt) {
            const long eb = (long)tt * MTILE + w * 64;
            #pragma unroll
            for (int mi = 0; mi < 4; ++mi) {
                const long e = eb + mi * 16 + ln;
                #pragma unroll
                for (int ks = 0; ks < 2; ++ks) {
                    xb[mi][ks][0] = X4[(size_t)e * 16 + 8 * ks + 2 * q];
                    xb[mi][ks][1] = X4[(size_t)e * 16 + 8 * ks + 2 * q + 1];
                }
            }
        };

        load(blockIdx.x);
        #pragma unroll 1
        for (int tile = blockIdx.x; tile < ntiles; tile += LGRID) {
            short8 bfr[4][2];
            #pragma unroll
            for (int mi = 0; mi < 4; ++mi)
                #pragma unroll
                for (int ks = 0; ks < 2; ++ks) {
                    float4 f0 = xb[mi][ks][0], f1 = xb[mi][ks][1];
                    short8 b;
                    b[0] = (short)f2bf(f0.x); b[1] = (short)f2bf(f0.y);
                    b[2] = (short)f2bf(f0.z); b[3] = (short)f2bf(f0.w);
                    b[4] = (short)f2bf(f1.x); b[5] = (short)f2bf(f1.y);
                    b[6] = (short)f2bf(f1.z); b[7] = (short)f2bf(f1.w);
                    bfr[mi][ks] = b;
                }
            if (tile + LGRID < ntiles) load(tile + LGRID);

            f32x4 acc[4][4];
            #pragma unroll
            for (int ni = 0; ni < 4; ++ni)
                #pragma unroll
                for (int mi = 0; mi < 4; ++mi)
                    acc[ni][mi] = (f32x4){0.f, 0.f, 0.f, 0.f};
            #pragma unroll
            for (int mi = 0; mi < 4; ++mi)
                #pragma unroll
                for (int ks = 0; ks < 2; ++ks)
                    #pragma unroll
                    for (int ni = 0; ni < 4; ++ni)
                        acc[ni][mi] = __builtin_amdgcn_mfma_f32_16x16x32_bf16(
                                          afr[ni][ks], bfr[mi][ks], acc[ni][mi], 0, 0, 0);
            store_acc(acc, tile);
        }
    }

    #pragma unroll
    for (int p = 0; p < 16; ++p) {
        #pragma unroll
        for (int m = 1; m < 16; m <<= 1) {
            ps[p] += __shfl_xor(ps[p], m);
            pq[p] += __shfl_xor(pq[p], m);
        }
    }
    if (ln == 0) {
        #pragma unroll
        for (int p = 0; p < 16; ++p) {
            int n = (p >> 2) * 16 + q * 4 + (p & 3);
            atomicAdd(&sh_s[n], ps[p]);
            atomicAdd(&sh_q[n], pq[p]);
        }
    }
    __syncthreads();
    if (t < F) {
        unsafeAtomicAdd(&stats_out[t], sh_s[t]);
        unsafeAtomicAdd(&stats_out[F + t], sh_q[t]);
    }
}

// Fused s + force, fully decentralized record emit: each block owns a fixed
// 256-record region. Records are counting-sorted by bucket in LDS, copied out
// with one coalesced 16B/lane store, plus a 16-entry prefix row. ZERO global
// atomics (the old 16 shared gcnt counters serialized 6250 same-address
// fabric atomics each, stalling every block at its barrier).
__global__ __launch_bounds__(TPB)
void force_bucket(const uint2* __restrict__ Yg, const float* __restrict__ stats,
                  const float* __restrict__ gamma, const float* __restrict__ beta,
                  const float* __restrict__ w_out, const float* __restrict__ b_out,
                  const float* __restrict__ nbr_shift, const float* __restrict__ pos,
                  const int* __restrict__ edge_index,
                  float4* __restrict__ recs, uint* __restrict__ pref,
                  int E, int R)
{
    __shared__ float ac[2 * F];
    __shared__ float wsh[F];
    __shared__ int lcnt[NB], lbase[NB];
    __shared__ float4 srt[TPB];
    const int t = threadIdx.x;
    if (t < F) {
        float inv_e = 1.f / (float)E;
        float mu = stats[t] * inv_e;
        float var = stats[F + t] * inv_e - mu * mu;
        float a = gamma[t] * rsqrtf(var + BN_EPS);
        ac[t] = a;
        ac[F + t] = beta[t] - mu * a;
        wsh[t] = w_out[t];
    }
    if (t < NB) lcnt[t] = 0;
    __syncthreads();

    const long e = (long)blockIdx.x * TPB + t;
    float4 rec = {0.f, 0.f, 0.f, __int_as_float(0)};
    int b = 0;

    if (e < E) {
        float s = b_out[0];
        #pragma unroll
        for (int nq = 0; nq < 16; ++nq) {
            uint2 u = Yg[(size_t)nq * E + e];
            int k = 4 * nq;
            float x0 = bf2f((ushort)(u.x & 0xffffu));
            float x1 = bf2f((ushort)(u.x >> 16));
            float x2 = bf2f((ushort)(u.y & 0xffffu));
            float x3 = bf2f((ushort)(u.y >> 16));
            s = fmaf(sp(ac[k]     * x0 + ac[F + k]),     wsh[k],     s);
            s = fmaf(sp(ac[k + 1] * x1 + ac[F + k + 1]), wsh[k + 1], s);
            s = fmaf(sp(ac[k + 2] * x2 + ac[F + k + 2]), wsh[k + 2], s);
            s = fmaf(sp(ac[k + 3] * x3 + ac[F + k + 3]), wsh[k + 3], s);
        }

        const int jn  = edge_index[e];       // source
        const int in_ = edge_index[E + e];   // target
        float dx = pos[3 * in_ + 0] + nbr_shift[3 * e + 0] - pos[3 * jn + 0];
        float dy = pos[3 * in_ + 1] + nbr_shift[3 * e + 1] - pos[3 * jn + 1];
        float dz = pos[3 * in_ + 2] + nbr_shift[3 * e + 2] - pos[3 * jn + 2];
        float inv = rsqrtf(dx * dx + dy * dy + dz * dz);
        float fs = s * inv;
        rec.x = fs * dx; rec.y = fs * dy; rec.z = fs * dz;
        rec.w = __int_as_float(in_);
        b = (int)((unsigned)in_ / (unsigned)R);
    }
    // padding threads (e>=E) emit a zero-force record for node 0, bucket 0 —
    // keeps counts summing to TPB with no special-casing downstream.
    int lrank = atomicAdd(&lcnt[b], 1);
    __syncthreads();
    if (t < NB) {                       // exclusive prefix (16 entries, trivial)
        int sacc = 0;
        for (int j = 0; j < t; ++j) sacc += lcnt[j];
        lbase[t] = sacc;
    }
    __syncthreads();
    srt[lbase[b] + lrank] = rec;        // counting-sort into LDS
    __syncthreads();
    recs[(size_t)blockIdx.x * TPB + t] = srt[t];   // coalesced region write
    if (t < NB) pref[blockIdx.x * NB + t] = (uint)lbase[t];
}

// Per-bucket LDS accumulation over the sorted per-block regions.
// 16 accum-blocks per bucket; each wave walks 4 source regions at a time
// (lane = 4 regions x 16 record-slots). Zero device-scope atomics.
__global__ __launch_bounds__(TPB)
void bucket_accum(const float4* __restrict__ recs, const uint* __restrict__ pref,
                  float* __restrict__ slabs, int R, int nsrc)
{
    __shared__ float acc[SLABSTRIDE];
    const int bucket = blockIdx.x / BPB;
    const int sub    = blockIdx.x - bucket * BPB;
    const int t = threadIdx.x;
    const int len = 3 * R;

    for (int i = t; i < len; i += TPB) acc[i] = 0.f;
    __syncthreads();

    const int wv = t >> 6;          // wave 0..3
    const int l  = t & 63;
    const int sg = l >> 4;          // 4 source regions per wave-iteration
    const int r  = l & 15;
    const int nbase = bucket * R;

    // 256 concurrent region streams: (sub*4 + wv)*4 + sg, stride 256
    for (int sb = (sub * 4 + wv) * 4 + sg; sb < nsrc; sb += BPB * 16) {
        uint st = pref[sb * NB + bucket];
        uint en = (bucket < NB - 1) ? pref[sb * NB + bucket + 1] : (uint)TPB;
        const float4* rg = recs + (size_t)sb * TPB;
        for (uint i = st + r; i < en; i += 16) {
            float4 rec = rg[i];
            int loc = 3 * (__float_as_int(rec.w) - nbase);
            atomicAdd(&acc[loc + 0], rec.x);
            atomicAdd(&acc[loc + 1], rec.y);
            atomicAdd(&acc[loc + 2], rec.z);
        }
    }
    __syncthreads();

    float* out = slabs + (size_t)blockIdx.x * SLABSTRIDE;
    for (int i = t; i < len; i += TPB) out[i] = acc[i];
}

// out[i] = sum over BPB slabs of this node's bucket.
__global__ __launch_bounds__(TPB)
void reduce_out(const float* __restrict__ slabs, float* __restrict__ out,
                int nodes3, int R)
{
    const int i = blockIdx.x * TPB + threadIdx.x;
    if (i >= nodes3) return;
    const int node = i / 3, c = i - 3 * node;
    const int bucket = node / R, loc = node - bucket * R;
    const size_t off = (size_t)(bucket * BPB) * SLABSTRIDE + 3 * loc + c;
    float s = 0.f;
    #pragma unroll
    for (int r = 0; r < BPB; ++r)
        s += slabs[off + (size_t)r * SLABSTRIDE];
    out[i] = s;
}

extern "C" void kernel_launch(void* const* d_in, const int* in_sizes, int n_in,
                              void* d_out, int out_size, void* d_ws, size_t ws_size,
                              hipStream_t stream)
{
    const int E = in_sizes[0] / F;                 // 1,600,000 (divisible by 256)
    const float* edge_attr = (const float*)d_in[0];
    const float* nbr_shift = (const float*)d_in[1];
    const float* pos       = (const float*)d_in[2];
    const float* Ws        = (const float*)d_in[3];   // [3][64][64]
    // d_in[4] (bs) unused: Linear bias cancels under BatchNorm
    const float* gammas    = (const float*)d_in[5];
    const float* betas     = (const float*)d_in[6];
    const float* w_out     = (const float*)d_in[7];
    const float* b_out     = (const float*)d_in[8];
    const int*   edge_index= (const int*)d_in[9];     // [2][E] int32

    const int nodes3 = out_size;                      // 150000 floats
    const int nodes  = nodes3 / 3;
    const int R = (nodes + NB - 1) / NB;              // 3125
    const int nsrc = (E + TPB - 1) / TPB;             // 6250 edge blocks

    char* p = (char*)d_ws;
    const size_t SZY = (size_t)E * F * 2;             // 204.8 MB per Y buffer
    uint2* Y1 = (uint2*)p;                 p += SZY;
    uint2* Y2 = (uint2*)p;                 p += SZY;
    float* stats = (float*)p;              p += 4096;
    float4* recs = (float4*)p;             p += (size_t)nsrc * TPB * 16;
    uint*  pref  = (uint*)p;               p += (size_t)nsrc * NB * 4;
    float* slabs = (float*)p;              p += (size_t)NB * BPB * SLABSTRIDE * 4;

    hipMemsetAsync(stats, 0, 6 * F * sizeof(float), stream);

    layer_mfma<0><<<LGRID, TPB, 0, stream>>>(edge_attr, Y1, Ws,
                                             nullptr, nullptr, nullptr, stats, E);
    layer_mfma<1><<<LGRID, TPB, 0, stream>>>(Y1, Y2, Ws + F * F,
                                             stats, gammas, betas, stats + 2 * F, E);
    layer_mfma<1><<<LGRID, TPB, 0, stream>>>(Y2, Y1, Ws + 2 * F * F,
                                             stats + 2 * F, gammas + F, betas + F,
                                             stats + 4 * F, E);
    force_bucket<<<nsrc, TPB, 0, stream>>>(
        Y1, stats + 4 * F, gammas + 2 * F, betas + 2 * F, w_out, b_out,
        nbr_shift, pos, edge_index, recs, pref, E, R);
    bucket_accum<<<NB * BPB, TPB, 0, stream>>>(recs, pref, slabs, R, nsrc);
    reduce_out<<<(nodes3 + TPB - 1) / TPB, TPB, 0, stream>>>(
        slabs, (float*)d_out, nodes3, R);
}